// Round 11
// baseline (1334.929 us; speedup 1.0000x reference)
//
#include <hip/hip_runtime.h>

#define DFEAT 64
#define BSHIFT 7                 // 128 nodes per bucket
#define BNODES 128
#define MAXB 1024                // supports n <= 131072 nodes, nb <= 1024 buckets
#define EPB 4096                 // edges per partition block

typedef unsigned int uint32;
typedef unsigned short ushort16;

// ---------- bf16 helpers ----------
__device__ __forceinline__ ushort16 f2bf(float f) {
    uint32 u = __float_as_uint(f);
    u += 0x7fffu + ((u >> 16) & 1u);   // round-to-nearest-even
    return (ushort16)(u >> 16);
}
__device__ __forceinline__ float bf_lo(uint32 u) { return __uint_as_float(u << 16); }
__device__ __forceinline__ float bf_hi(uint32 u) { return __uint_as_float(u & 0xffff0000u); }

// ---------- P1: per-block bucket histogram ----------
__global__ __launch_bounds__(256) void k_p1(
    const int* __restrict__ dst, int E, int* __restrict__ hist, int nblk, int nb) {
    __shared__ int h[MAXB];
    for (int i = threadIdx.x; i < nb; i += 256) h[i] = 0;
    __syncthreads();
    int base = blockIdx.x * EPB;
    int lim = E - base; if (lim > EPB) lim = EPB;
    for (int j = threadIdx.x; j < lim; j += 256)
        atomicAdd(&h[dst[base + j] >> BSHIFT], 1);
    __syncthreads();
    for (int i = threadIdx.x; i < nb; i += 256)
        hist[(size_t)i * nblk + blockIdx.x] = h[i];   // bucket-major rows
}

// ---------- P2a: bucket totals (one wave per bucket) ----------
__global__ __launch_bounds__(256) void k_p2a(
    const int* __restrict__ hist, int nblk, int nb, int* __restrict__ btot) {
    int w = (blockIdx.x * 256 + threadIdx.x) >> 6;
    int lane = threadIdx.x & 63;
    if (w >= nb) return;
    size_t base = (size_t)w * nblk;
    int s = 0;
    for (int k = lane; k < nblk; k += 64) s += hist[base + k];
#pragma unroll
    for (int d = 1; d < 64; d <<= 1) s += __shfl_xor(s, d, 64);
    if (lane == 0) btot[w] = s;
}

// ---------- P2b: exclusive scan of bucket totals (nb <= 1024) ----------
__global__ __launch_bounds__(256) void k_p2b(
    const int* __restrict__ btot, int nb, int* __restrict__ bstart) {
    __shared__ int lds[256];
    __shared__ int pre[257];
    int t = threadIdx.x;
    int c0 = t * 4;
    int v[4]; int s = 0;
#pragma unroll
    for (int j = 0; j < 4; ++j) { v[j] = (c0 + j < nb) ? btot[c0 + j] : 0; s += v[j]; }
    lds[t] = s; __syncthreads();
    if (t == 0) { int run = 0; for (int i = 0; i < 256; ++i) { pre[i] = run; run += lds[i]; } pre[256] = run; }
    __syncthreads();
    int run = pre[t];
#pragma unroll
    for (int j = 0; j < 4; ++j) {
        if (c0 + j < nb) bstart[c0 + j] = run;
        run += v[j];
    }
    if (t == 0) bstart[nb] = pre[256];   // = E
}

// ---------- P2c: per-(bucket,block) global offsets, wave-parallel scan per bucket ----------
__global__ __launch_bounds__(256) void k_p2c(
    int* __restrict__ hist, int nblk, int nb, const int* __restrict__ bstart) {
    int w = (blockIdx.x * 256 + threadIdx.x) >> 6;
    int lane = threadIdx.x & 63;
    if (w >= nb) return;
    size_t base = (size_t)w * nblk;
    int run = bstart[w];
    for (int c = 0; c < nblk; c += 64) {
        int k = c + lane;
        int v = (k < nblk) ? hist[base + k] : 0;
        int sc = v;
#pragma unroll
        for (int d = 1; d < 64; d <<= 1) { int t = __shfl_up(sc, d, 64); if (lane >= d) sc += t; }
        if (k < nblk) hist[base + k] = run + sc - v;   // exclusive
        run += __shfl(sc, 63, 64);
    }
}

// ---------- P3: partition scatter, packed records src | dstLocal<<17 ----------
__global__ __launch_bounds__(256) void k_p3(
    const int* __restrict__ src, const int* __restrict__ dst, int E,
    const int* __restrict__ hist, int nblk, int nb, uint32* __restrict__ part) {
    __shared__ int cur[MAXB];
    for (int i = threadIdx.x; i < nb; i += 256) cur[i] = hist[(size_t)i * nblk + blockIdx.x];
    __syncthreads();
    int base = blockIdx.x * EPB;
    int lim = E - base; if (lim > EPB) lim = EPB;
    for (int j = threadIdx.x; j < lim; j += 256) {
        int d = dst[base + j];
        int s = src[base + j];
        int b = d >> BSHIFT;
        int pos = atomicAdd(&cur[b], 1);
        part[pos] = (uint32)s | ((uint32)(d & (BNODES - 1)) << 17);
    }
}

// ---------- per-bucket counting sort -> CSR (row_ptr, col) + dis ----------
__global__ __launch_bounds__(256) void k_sort(
    const uint32* __restrict__ part, const int* __restrict__ bstart,
    int* __restrict__ row_ptr, int* __restrict__ col, float* __restrict__ dis,
    int n, int nb) {
    __shared__ int cnt[BNODES];
    __shared__ int off[BNODES + 1];
    int b = blockIdx.x;
    int node0 = b << BSHIFT;
    int nn = n - node0; if (nn > BNODES) nn = BNODES;

    if (threadIdx.x < BNODES) cnt[threadIdx.x] = 0;
    __syncthreads();
    int beg = bstart[b], end = bstart[b + 1];
    for (int i = beg + threadIdx.x; i < end; i += 256)
        atomicAdd(&cnt[part[i] >> 17], 1);
    __syncthreads();
    if (threadIdx.x == 0) {
        int run = beg;
        for (int j = 0; j < BNODES; ++j) { off[j] = run; run += cnt[j]; }
        off[BNODES] = run;
    }
    __syncthreads();
    if (threadIdx.x < nn) {
        row_ptr[node0 + threadIdx.x] = off[threadIdx.x];
        dis[node0 + threadIdx.x] = rsqrtf((float)cnt[threadIdx.x] + 1.0f);  // +1 self-loop
    }
    if (b == nb - 1 && threadIdx.x == 0) row_ptr[n] = end;
    if (threadIdx.x < BNODES) cnt[threadIdx.x] = 0;   // reuse as cursor
    __syncthreads();
    for (int i = beg + threadIdx.x; i < end; i += 256) {
        uint32 p = part[i];
        int j = p >> 17;
        int pos = off[j] + atomicAdd(&cnt[j], 1);
        col[pos] = (int)(p & 0x1FFFFu);    // global src id (n < 2^17)
    }
}

// ---------- tall-skinny GEMM: g_bf16 = bf16((X @ W) * dis) ----------
// k-unrolled x4: per 4 k-steps, 4 strided b32 Ws reads + 16 float4 Xs broadcasts + 64 FMA.
__global__ __launch_bounds__(256) void k_gemm_scale(
    const float* __restrict__ X, const float* __restrict__ W,
    const float* __restrict__ dis, ushort16* __restrict__ gb, int n) {
    __shared__ float Ws[64 * 64];
    __shared__ float Xs[64 * 64];

    {   // float4 staging
        float4* Wv = (float4*)Ws;
        const float4* Wg = (const float4*)W;
        for (int i = threadIdx.x; i < 64 * 16; i += 256) Wv[i] = Wg[i];
    }
    int row0 = blockIdx.x * 64;
    int rows = n - row0; if (rows > 64) rows = 64;
    {
        float4* Xv = (float4*)Xs;
        const float4* Xg = (const float4*)(X + (size_t)row0 * 64);
        for (int i = threadIdx.x; i < rows * 16; i += 256) Xv[i] = Xg[i];
    }
    __syncthreads();

    int d  = threadIdx.x & 63;
    int rg = threadIdx.x >> 6;

    float acc[16];
#pragma unroll
    for (int r = 0; r < 16; ++r) acc[r] = 0.f;

#pragma unroll
    for (int k4 = 0; k4 < 64; k4 += 4) {
        float w0 = Ws[(k4 + 0) * 64 + d];
        float w1 = Ws[(k4 + 1) * 64 + d];
        float w2 = Ws[(k4 + 2) * 64 + d];
        float w3 = Ws[(k4 + 3) * 64 + d];
#pragma unroll
        for (int r = 0; r < 16; ++r) {
            float4 xv = *reinterpret_cast<const float4*>(&Xs[(rg * 16 + r) * 64 + k4]);
            acc[r] = fmaf(xv.x, w0, acc[r]);
            acc[r] = fmaf(xv.y, w1, acc[r]);
            acc[r] = fmaf(xv.z, w2, acc[r]);
            acc[r] = fmaf(xv.w, w3, acc[r]);
        }
    }

#pragma unroll
    for (int r = 0; r < 16; ++r) {
        int row = rg * 16 + r;
        if (row < rows)
            gb[(size_t)(row0 + row) * 64 + d] = f2bf(acc[r] * dis[row0 + row]);
    }
}

// ---------- fused aggregate + epilogue (wave per node, deep-MLP bf16 gather) ----------
// Lane = (slot 0..7) x (chunk 0..7). Each lane loads uint4 (8 bf16 feats) of row
// col[slot]; 16 virtual edges (self + neighbors, clamped/masked) per iteration ->
// 16 rows in flight per wave. 3-round shfl_xor folds the 8 slots at the end.
__global__ __launch_bounds__(256) void k_aggregate(
    const ushort16* __restrict__ gb, const int* __restrict__ row_ptr,
    const int* __restrict__ col, const float* __restrict__ dis,
    const float* __restrict__ bias, const float* __restrict__ resid,
    float* __restrict__ out, int n) {
    int node = blockIdx.x * 4 + (threadIdx.x >> 6);
    if (node >= n) return;
    int lane = threadIdx.x & 63;
    int slot = lane >> 3;     // edge slot 0..7
    int q    = lane & 7;      // 16B chunk 0..7 (feats q*8 .. q*8+7)
    const uint4* gq = (const uint4*)gb;   // row = 8 uint4

    int beg = row_ptr[node], end = row_ptr[node + 1];
    int T = end - beg + 1;    // virtual edges: index 0 = self, 1.. = neighbors

    float acc[8];
#pragma unroll
    for (int j = 0; j < 8; ++j) acc[j] = 0.f;

    for (int i = 0; i < T; i += 16) {
        int v0 = i + slot;
        int v1 = i + 8 + slot;
        int vc0 = v0 < T - 1 ? v0 : T - 1;
        int vc1 = v1 < T - 1 ? v1 : T - 1;
        int c0 = (vc0 == 0) ? node : col[beg + vc0 - 1];
        int c1 = (vc1 == 0) ? node : col[beg + vc1 - 1];
        uint4 u0 = gq[(size_t)c0 * 8 + q];
        uint4 u1 = gq[(size_t)c1 * 8 + q];
        float w0 = (v0 < T) ? 1.f : 0.f;
        float w1 = (v1 < T) ? 1.f : 0.f;
        acc[0] = fmaf(w0, bf_lo(u0.x), acc[0]); acc[1] = fmaf(w0, bf_hi(u0.x), acc[1]);
        acc[2] = fmaf(w0, bf_lo(u0.y), acc[2]); acc[3] = fmaf(w0, bf_hi(u0.y), acc[3]);
        acc[4] = fmaf(w0, bf_lo(u0.z), acc[4]); acc[5] = fmaf(w0, bf_hi(u0.z), acc[5]);
        acc[6] = fmaf(w0, bf_lo(u0.w), acc[6]); acc[7] = fmaf(w0, bf_hi(u0.w), acc[7]);
        acc[0] = fmaf(w1, bf_lo(u1.x), acc[0]); acc[1] = fmaf(w1, bf_hi(u1.x), acc[1]);
        acc[2] = fmaf(w1, bf_lo(u1.y), acc[2]); acc[3] = fmaf(w1, bf_hi(u1.y), acc[3]);
        acc[4] = fmaf(w1, bf_lo(u1.z), acc[4]); acc[5] = fmaf(w1, bf_hi(u1.z), acc[5]);
        acc[6] = fmaf(w1, bf_lo(u1.w), acc[6]); acc[7] = fmaf(w1, bf_hi(u1.w), acc[7]);
    }

    // fold the 8 slots (lanes q, q+8, ..., q+56)
#pragma unroll
    for (int j = 0; j < 8; ++j) {
        acc[j] += __shfl_xor(acc[j], 8, 64);
        acc[j] += __shfl_xor(acc[j], 16, 64);
        acc[j] += __shfl_xor(acc[j], 32, 64);
    }

    if (slot == 0) {          // lanes 0..7, lane == q
        float dn = dis[node];
        float r[8];
#pragma unroll
        for (int j = 0; j < 8; ++j)
            r[j] = fmaxf(fmaf(acc[j], dn, bias[q * 8 + j]), 0.f);
        if (resid) {
            const float4* rv = (const float4*)(resid + (size_t)node * DFEAT + q * 8);
            float4 x0 = rv[0], x1 = rv[1];
            r[0] += x0.x; r[1] += x0.y; r[2] += x0.z; r[3] += x0.w;
            r[4] += x1.x; r[5] += x1.y; r[6] += x1.z; r[7] += x1.w;
        }
        float4* ov = (float4*)(out + (size_t)node * DFEAT + q * 8);
        ov[0] = make_float4(r[0], r[1], r[2], r[3]);
        ov[1] = make_float4(r[4], r[5], r[6], r[7]);
    }
}

// ======================= launch =======================

extern "C" void kernel_launch(void* const* d_in, const int* in_sizes, int n_in,
                              void* d_out, int out_size, void* d_ws, size_t ws_size,
                              hipStream_t stream) {
    const float* x  = (const float*)d_in[0];
    const int*   ei = (const int*)  d_in[1];
    const float* W1 = (const float*)d_in[2];
    const float* b1 = (const float*)d_in[3];
    const float* W2 = (const float*)d_in[4];
    const float* b2 = (const float*)d_in[5];
    float* out = (float*)d_out;

    const int n = in_sizes[0] / DFEAT;     // 100000
    const int E = in_sizes[1] / 2;         // 1250000
    const int* src = ei;
    const int* dst = ei + E;

    const int nb   = (n + BNODES - 1) >> BSHIFT;     // 782 buckets
    const int nblk = (E + EPB - 1) / EPB;            // 306 partition blocks

    // workspace carve-up (4B elems)
    int*      hist    = (int*)d_ws;                                  // nb*nblk
    int*      btot    = hist + (((size_t)nb * nblk + 3) & ~3);       // nb
    int*      bstart  = btot + ((nb + 3) & ~3);                      // nb+1
    uint32*   part    = (uint32*)(bstart + ((nb + 1 + 3) & ~3));     // E
    int*      row_ptr = (int*)(part + ((E + 3) & ~3));               // n+1
    int*      col     = row_ptr + ((n + 1 + 3) & ~3);                // E
    float*    dis     = (float*)(col + ((E + 3) & ~3));              // n
    ushort16* gb      = (ushort16*)(dis + ((n + 3) & ~3));           // n*64 bf16
    float*    h       = (float*)(gb + (size_t)n * DFEAT);            // n*64 f32

    const int B256 = 256;
    const int gT   = (n + 63) / 64;
    const int gW   = ((nb * 64) + B256 - 1) / B256;   // wave-per-bucket kernels
    const int gAg  = (n + 3) / 4;

    // ---- bucket partition + per-bucket sort -> CSR ----
    k_p1  <<<nblk, B256, 0, stream>>>(dst, E, hist, nblk, nb);
    k_p2a <<<gW,   B256, 0, stream>>>(hist, nblk, nb, btot);
    k_p2b <<<1,    B256, 0, stream>>>(btot, nb, bstart);
    k_p2c <<<gW,   B256, 0, stream>>>(hist, nblk, nb, bstart);
    k_p3  <<<nblk, B256, 0, stream>>>(src, dst, E, hist, nblk, nb, part);
    k_sort<<<nb,   B256, 0, stream>>>(part, bstart, row_ptr, col, dis, n, nb);

    // ---- layer 1 ----
    k_gemm_scale<<<gT,  B256, 0, stream>>>(x, W1, dis, gb, n);
    k_aggregate <<<gAg, B256, 0, stream>>>(gb, row_ptr, col, dis, b1, nullptr, h, n);

    // ---- layer 2 ----
    k_gemm_scale<<<gT,  B256, 0, stream>>>(h, W2, dis, gb, n);
    k_aggregate <<<gAg, B256, 0, stream>>>(gb, row_ptr, col, dis, b2, x, out, n);
}

// Round 13
// 271.802 us; speedup vs baseline: 4.9114x; 4.9114x over previous
//
#include <hip/hip_runtime.h>

#define DFEAT 64
#define BSHIFT 7                 // 128 nodes per bucket
#define BNODES 128
#define MAXB 1024                // supports n <= 131072 nodes, nb <= 1024 buckets
#define EPB 4096                 // edges per partition block

typedef unsigned int uint32;
typedef unsigned short ushort16;

// ---------- bf16 helpers ----------
__device__ __forceinline__ ushort16 f2bf(float f) {
    uint32 u = __float_as_uint(f);
    u += 0x7fffu + ((u >> 16) & 1u);   // round-to-nearest-even
    return (ushort16)(u >> 16);
}
__device__ __forceinline__ float bf_lo(uint32 u) { return __uint_as_float(u << 16); }
__device__ __forceinline__ float bf_hi(uint32 u) { return __uint_as_float(u & 0xffff0000u); }

// ---------- P1: per-block bucket histogram ----------
__global__ __launch_bounds__(256) void k_p1(
    const int* __restrict__ dst, int E, int* __restrict__ hist, int nblk, int nb) {
    __shared__ int h[MAXB];
    for (int i = threadIdx.x; i < nb; i += 256) h[i] = 0;
    __syncthreads();
    int base = blockIdx.x * EPB;
    int lim = E - base; if (lim > EPB) lim = EPB;
    for (int j = threadIdx.x; j < lim; j += 256)
        atomicAdd(&h[dst[base + j] >> BSHIFT], 1);
    __syncthreads();
    for (int i = threadIdx.x; i < nb; i += 256)
        hist[(size_t)i * nblk + blockIdx.x] = h[i];   // bucket-major rows
}

// ---------- P2a: bucket totals (one wave per bucket) ----------
__global__ __launch_bounds__(256) void k_p2a(
    const int* __restrict__ hist, int nblk, int nb, int* __restrict__ btot) {
    int w = (blockIdx.x * 256 + threadIdx.x) >> 6;
    int lane = threadIdx.x & 63;
    if (w >= nb) return;
    size_t base = (size_t)w * nblk;
    int s = 0;
    for (int k = lane; k < nblk; k += 64) s += hist[base + k];
#pragma unroll
    for (int d = 1; d < 64; d <<= 1) s += __shfl_xor(s, d, 64);
    if (lane == 0) btot[w] = s;
}

// ---------- P2b: exclusive scan of bucket totals (nb <= 1024) ----------
__global__ __launch_bounds__(256) void k_p2b(
    const int* __restrict__ btot, int nb, int* __restrict__ bstart) {
    __shared__ int lds[256];
    __shared__ int pre[257];
    int t = threadIdx.x;
    int c0 = t * 4;
    int v[4]; int s = 0;
#pragma unroll
    for (int j = 0; j < 4; ++j) { v[j] = (c0 + j < nb) ? btot[c0 + j] : 0; s += v[j]; }
    lds[t] = s; __syncthreads();
    if (t == 0) { int run = 0; for (int i = 0; i < 256; ++i) { pre[i] = run; run += lds[i]; } pre[256] = run; }
    __syncthreads();
    int run = pre[t];
#pragma unroll
    for (int j = 0; j < 4; ++j) {
        if (c0 + j < nb) bstart[c0 + j] = run;
        run += v[j];
    }
    if (t == 0) bstart[nb] = pre[256];   // = E
}

// ---------- P2c: per-(bucket,block) global offsets, wave-parallel scan per bucket ----------
__global__ __launch_bounds__(256) void k_p2c(
    int* __restrict__ hist, int nblk, int nb, const int* __restrict__ bstart) {
    int w = (blockIdx.x * 256 + threadIdx.x) >> 6;
    int lane = threadIdx.x & 63;
    if (w >= nb) return;
    size_t base = (size_t)w * nblk;
    int run = bstart[w];
    for (int c = 0; c < nblk; c += 64) {
        int k = c + lane;
        int v = (k < nblk) ? hist[base + k] : 0;
        int sc = v;
#pragma unroll
        for (int d = 1; d < 64; d <<= 1) { int t = __shfl_up(sc, d, 64); if (lane >= d) sc += t; }
        if (k < nblk) hist[base + k] = run + sc - v;   // exclusive
        run += __shfl(sc, 63, 64);
    }
}

// ---------- P3: partition scatter, packed records src | dstLocal<<17 ----------
__global__ __launch_bounds__(256) void k_p3(
    const int* __restrict__ src, const int* __restrict__ dst, int E,
    const int* __restrict__ hist, int nblk, int nb, uint32* __restrict__ part) {
    __shared__ int cur[MAXB];
    for (int i = threadIdx.x; i < nb; i += 256) cur[i] = hist[(size_t)i * nblk + blockIdx.x];
    __syncthreads();
    int base = blockIdx.x * EPB;
    int lim = E - base; if (lim > EPB) lim = EPB;
    for (int j = threadIdx.x; j < lim; j += 256) {
        int d = dst[base + j];
        int s = src[base + j];
        int b = d >> BSHIFT;
        int pos = atomicAdd(&cur[b], 1);
        part[pos] = (uint32)s | ((uint32)(d & (BNODES - 1)) << 17);
    }
}

// ---------- per-bucket counting sort -> CSR (row_ptr, col) + dis ----------
__global__ __launch_bounds__(256) void k_sort(
    const uint32* __restrict__ part, const int* __restrict__ bstart,
    int* __restrict__ row_ptr, int* __restrict__ col, float* __restrict__ dis,
    int n, int nb) {
    __shared__ int cnt[BNODES];
    __shared__ int off[BNODES + 1];
    int b = blockIdx.x;
    int node0 = b << BSHIFT;
    int nn = n - node0; if (nn > BNODES) nn = BNODES;

    if (threadIdx.x < BNODES) cnt[threadIdx.x] = 0;
    __syncthreads();
    int beg = bstart[b], end = bstart[b + 1];
    for (int i = beg + threadIdx.x; i < end; i += 256)
        atomicAdd(&cnt[part[i] >> 17], 1);
    __syncthreads();
    if (threadIdx.x == 0) {
        int run = beg;
        for (int j = 0; j < BNODES; ++j) { off[j] = run; run += cnt[j]; }
        off[BNODES] = run;
    }
    __syncthreads();
    if (threadIdx.x < nn) {
        row_ptr[node0 + threadIdx.x] = off[threadIdx.x];
        dis[node0 + threadIdx.x] = rsqrtf((float)cnt[threadIdx.x] + 1.0f);  // +1 self-loop
    }
    if (b == nb - 1 && threadIdx.x == 0) row_ptr[n] = end;
    if (threadIdx.x < BNODES) cnt[threadIdx.x] = 0;   // reuse as cursor
    __syncthreads();
    for (int i = beg + threadIdx.x; i < end; i += 256) {
        uint32 p = part[i];
        int j = p >> 17;
        int pos = off[j] + atomicAdd(&cnt[j], 1);
        col[pos] = (int)(p & 0x1FFFFu);    // global src id (n < 2^17)
    }
}

// ---------- tall-skinny GEMM: g_bf16 = bf16((X @ W) * dis) ----------
// R6-proven inner loop (scalar broadcast FMAs, no spills); float4 staging only.
__global__ __launch_bounds__(256) void k_gemm_scale(
    const float* __restrict__ X, const float* __restrict__ W,
    const float* __restrict__ dis, ushort16* __restrict__ gb, int n) {
    __shared__ float Ws[64 * 64];
    __shared__ float Xs[64 * 64];

    {   // float4 staging
        float4* Wv = (float4*)Ws;
        const float4* Wg = (const float4*)W;
        for (int i = threadIdx.x; i < 64 * 16; i += 256) Wv[i] = Wg[i];
    }
    int row0 = blockIdx.x * 64;
    int rows = n - row0; if (rows > 64) rows = 64;
    {
        float4* Xv = (float4*)Xs;
        const float4* Xg = (const float4*)(X + (size_t)row0 * 64);
        for (int i = threadIdx.x; i < rows * 16; i += 256) Xv[i] = Xg[i];
    }
    __syncthreads();

    int d  = threadIdx.x & 63;
    int rg = threadIdx.x >> 6;

    float acc[16];
#pragma unroll
    for (int r = 0; r < 16; ++r) acc[r] = 0.f;

#pragma unroll 16
    for (int k = 0; k < 64; ++k) {
        float w = Ws[k * 64 + d];
#pragma unroll
        for (int r = 0; r < 16; ++r)
            acc[r] = fmaf(Xs[(rg * 16 + r) * 64 + k], w, acc[r]);
    }

#pragma unroll
    for (int r = 0; r < 16; ++r) {
        int row = rg * 16 + r;
        if (row < rows)
            gb[(size_t)(row0 + row) * 64 + d] = f2bf(acc[r] * dis[row0 + row]);
    }
}

// ---------- fused aggregate + epilogue (wave per node, deep-MLP bf16 gather) ----------
// Lane = (slot 0..7) x (chunk 0..7). Each lane loads uint4 (8 bf16 feats) of row
// col[slot]; 16 virtual edges (self + neighbors, clamped/masked) per iteration ->
// 16 rows in flight per wave. 3-round shfl_xor folds the 8 slots at the end.
__global__ __launch_bounds__(256) void k_aggregate(
    const ushort16* __restrict__ gb, const int* __restrict__ row_ptr,
    const int* __restrict__ col, const float* __restrict__ dis,
    const float* __restrict__ bias, const float* __restrict__ resid,
    float* __restrict__ out, int n) {
    int node = blockIdx.x * 4 + (threadIdx.x >> 6);
    if (node >= n) return;
    int lane = threadIdx.x & 63;
    int slot = lane >> 3;     // edge slot 0..7
    int q    = lane & 7;      // 16B chunk 0..7 (feats q*8 .. q*8+7)
    const uint4* gq = (const uint4*)gb;   // row = 8 uint4

    int beg = row_ptr[node], end = row_ptr[node + 1];
    int T = end - beg + 1;    // virtual edges: index 0 = self, 1.. = neighbors

    float acc[8];
#pragma unroll
    for (int j = 0; j < 8; ++j) acc[j] = 0.f;

    for (int i = 0; i < T; i += 16) {
        int v0 = i + slot;
        int v1 = i + 8 + slot;
        int vc0 = v0 < T - 1 ? v0 : T - 1;
        int vc1 = v1 < T - 1 ? v1 : T - 1;
        int c0 = (vc0 == 0) ? node : col[beg + vc0 - 1];
        int c1 = (vc1 == 0) ? node : col[beg + vc1 - 1];
        uint4 u0 = gq[(size_t)c0 * 8 + q];
        uint4 u1 = gq[(size_t)c1 * 8 + q];
        float w0 = (v0 < T) ? 1.f : 0.f;
        float w1 = (v1 < T) ? 1.f : 0.f;
        acc[0] = fmaf(w0, bf_lo(u0.x), acc[0]); acc[1] = fmaf(w0, bf_hi(u0.x), acc[1]);
        acc[2] = fmaf(w0, bf_lo(u0.y), acc[2]); acc[3] = fmaf(w0, bf_hi(u0.y), acc[3]);
        acc[4] = fmaf(w0, bf_lo(u0.z), acc[4]); acc[5] = fmaf(w0, bf_hi(u0.z), acc[5]);
        acc[6] = fmaf(w0, bf_lo(u0.w), acc[6]); acc[7] = fmaf(w0, bf_hi(u0.w), acc[7]);
        acc[0] = fmaf(w1, bf_lo(u1.x), acc[0]); acc[1] = fmaf(w1, bf_hi(u1.x), acc[1]);
        acc[2] = fmaf(w1, bf_lo(u1.y), acc[2]); acc[3] = fmaf(w1, bf_hi(u1.y), acc[3]);
        acc[4] = fmaf(w1, bf_lo(u1.z), acc[4]); acc[5] = fmaf(w1, bf_hi(u1.z), acc[5]);
        acc[6] = fmaf(w1, bf_lo(u1.w), acc[6]); acc[7] = fmaf(w1, bf_hi(u1.w), acc[7]);
    }

    // fold the 8 slots (lanes q, q+8, ..., q+56)
#pragma unroll
    for (int j = 0; j < 8; ++j) {
        acc[j] += __shfl_xor(acc[j], 8, 64);
        acc[j] += __shfl_xor(acc[j], 16, 64);
        acc[j] += __shfl_xor(acc[j], 32, 64);
    }

    if (slot == 0) {          // lanes 0..7, lane == q
        float dn = dis[node];
        float r[8];
#pragma unroll
        for (int j = 0; j < 8; ++j)
            r[j] = fmaxf(fmaf(acc[j], dn, bias[q * 8 + j]), 0.f);
        if (resid) {
            const float4* rv = (const float4*)(resid + (size_t)node * DFEAT + q * 8);
            float4 x0 = rv[0], x1 = rv[1];
            r[0] += x0.x; r[1] += x0.y; r[2] += x0.z; r[3] += x0.w;
            r[4] += x1.x; r[5] += x1.y; r[6] += x1.z; r[7] += x1.w;
        }
        float4* ov = (float4*)(out + (size_t)node * DFEAT + q * 8);
        ov[0] = make_float4(r[0], r[1], r[2], r[3]);
        ov[1] = make_float4(r[4], r[5], r[6], r[7]);
    }
}

// ======================= launch =======================

extern "C" void kernel_launch(void* const* d_in, const int* in_sizes, int n_in,
                              void* d_out, int out_size, void* d_ws, size_t ws_size,
                              hipStream_t stream) {
    const float* x  = (const float*)d_in[0];
    const int*   ei = (const int*)  d_in[1];
    const float* W1 = (const float*)d_in[2];
    const float* b1 = (const float*)d_in[3];
    const float* W2 = (const float*)d_in[4];
    const float* b2 = (const float*)d_in[5];
    float* out = (float*)d_out;

    const int n = in_sizes[0] / DFEAT;     // 100000
    const int E = in_sizes[1] / 2;         // 1250000
    const int* src = ei;
    const int* dst = ei + E;

    const int nb   = (n + BNODES - 1) >> BSHIFT;     // 782 buckets
    const int nblk = (E + EPB - 1) / EPB;            // 306 partition blocks

    // workspace carve-up (4B elems)
    int*      hist    = (int*)d_ws;                                  // nb*nblk
    int*      btot    = hist + (((size_t)nb * nblk + 3) & ~3);       // nb
    int*      bstart  = btot + ((nb + 3) & ~3);                      // nb+1
    uint32*   part    = (uint32*)(bstart + ((nb + 1 + 3) & ~3));     // E
    int*      row_ptr = (int*)(part + ((E + 3) & ~3));               // n+1
    int*      col     = row_ptr + ((n + 1 + 3) & ~3);                // E
    float*    dis     = (float*)(col + ((E + 3) & ~3));              // n
    ushort16* gb      = (ushort16*)(dis + ((n + 3) & ~3));           // n*64 bf16
    float*    h       = (float*)(gb + (size_t)n * DFEAT);            // n*64 f32

    const int B256 = 256;
    const int gT   = (n + 63) / 64;
    const int gW   = ((nb * 64) + B256 - 1) / B256;   // wave-per-bucket kernels
    const int gAg  = (n + 3) / 4;

    // ---- bucket partition + per-bucket sort -> CSR ----
    k_p1  <<<nblk, B256, 0, stream>>>(dst, E, hist, nblk, nb);
    k_p2a <<<gW,   B256, 0, stream>>>(hist, nblk, nb, btot);
    k_p2b <<<1,    B256, 0, stream>>>(btot, nb, bstart);
    k_p2c <<<gW,   B256, 0, stream>>>(hist, nblk, nb, bstart);
    k_p3  <<<nblk, B256, 0, stream>>>(src, dst, E, hist, nblk, nb, part);
    k_sort<<<nb,   B256, 0, stream>>>(part, bstart, row_ptr, col, dis, n, nb);

    // ---- layer 1 ----
    k_gemm_scale<<<gT,  B256, 0, stream>>>(x, W1, dis, gb, n);
    k_aggregate <<<gAg, B256, 0, stream>>>(gb, row_ptr, col, dis, b1, nullptr, h, n);

    // ---- layer 2 ----
    k_gemm_scale<<<gT,  B256, 0, stream>>>(h, W2, dis, gb, n);
    k_aggregate <<<gAg, B256, 0, stream>>>(gb, row_ptr, col, dis, b2, x, out, n);
}

// Round 16
// 239.685 us; speedup vs baseline: 5.5695x; 1.1340x over previous
//
#include <hip/hip_runtime.h>

#define DFEAT 64
#define BSHIFT 7                 // 128 nodes per bucket
#define BNODES 128
#define MAXB 1024                // supports n <= 131072 nodes, nb <= 1024 buckets
#define EPB 4096                 // edges per partition block
#define XPAD 68                  // Xs row stride (pad 4 floats: 2-way bank alias, free)

typedef unsigned int uint32;
typedef unsigned short ushort16;

// ---------- bf16 helpers ----------
__device__ __forceinline__ ushort16 f2bf(float f) {
    uint32 u = __float_as_uint(f);
    u += 0x7fffu + ((u >> 16) & 1u);   // round-to-nearest-even
    return (ushort16)(u >> 16);
}
__device__ __forceinline__ float bf_lo(uint32 u) { return __uint_as_float(u << 16); }
__device__ __forceinline__ float bf_hi(uint32 u) { return __uint_as_float(u & 0xffff0000u); }

// ---------- P1: per-block bucket histogram ----------
__global__ __launch_bounds__(256) void k_p1(
    const int* __restrict__ dst, int E, int* __restrict__ hist, int nblk, int nb) {
    __shared__ int h[MAXB];
    for (int i = threadIdx.x; i < nb; i += 256) h[i] = 0;
    __syncthreads();
    int base = blockIdx.x * EPB;
    int lim = E - base; if (lim > EPB) lim = EPB;
    for (int j = threadIdx.x; j < lim; j += 256)
        atomicAdd(&h[dst[base + j] >> BSHIFT], 1);
    __syncthreads();
    for (int i = threadIdx.x; i < nb; i += 256)
        hist[(size_t)i * nblk + blockIdx.x] = h[i];   // bucket-major rows
}

// ---------- P2a: bucket totals (one wave per bucket) ----------
__global__ __launch_bounds__(256) void k_p2a(
    const int* __restrict__ hist, int nblk, int nb, int* __restrict__ btot) {
    int w = (blockIdx.x * 256 + threadIdx.x) >> 6;
    int lane = threadIdx.x & 63;
    if (w >= nb) return;
    size_t base = (size_t)w * nblk;
    int s = 0;
    for (int k = lane; k < nblk; k += 64) s += hist[base + k];
#pragma unroll
    for (int d = 1; d < 64; d <<= 1) s += __shfl_xor(s, d, 64);
    if (lane == 0) btot[w] = s;
}

// ---------- P2b: exclusive scan of bucket totals (nb <= 1024) ----------
__global__ __launch_bounds__(256) void k_p2b(
    const int* __restrict__ btot, int nb, int* __restrict__ bstart) {
    __shared__ int lds[256];
    __shared__ int pre[257];
    int t = threadIdx.x;
    int c0 = t * 4;
    int v[4]; int s = 0;
#pragma unroll
    for (int j = 0; j < 4; ++j) { v[j] = (c0 + j < nb) ? btot[c0 + j] : 0; s += v[j]; }
    lds[t] = s; __syncthreads();
    if (t == 0) { int run = 0; for (int i = 0; i < 256; ++i) { pre[i] = run; run += lds[i]; } pre[256] = run; }
    __syncthreads();
    int run = pre[t];
#pragma unroll
    for (int j = 0; j < 4; ++j) {
        if (c0 + j < nb) bstart[c0 + j] = run;
        run += v[j];
    }
    if (t == 0) bstart[nb] = pre[256];   // = E
}

// ---------- P2c: per-(bucket,block) global offsets, wave-parallel scan per bucket ----------
__global__ __launch_bounds__(256) void k_p2c(
    int* __restrict__ hist, int nblk, int nb, const int* __restrict__ bstart) {
    int w = (blockIdx.x * 256 + threadIdx.x) >> 6;
    int lane = threadIdx.x & 63;
    if (w >= nb) return;
    size_t base = (size_t)w * nblk;
    int run = bstart[w];
    for (int c = 0; c < nblk; c += 64) {
        int k = c + lane;
        int v = (k < nblk) ? hist[base + k] : 0;
        int sc = v;
#pragma unroll
        for (int d = 1; d < 64; d <<= 1) { int t = __shfl_up(sc, d, 64); if (lane >= d) sc += t; }
        if (k < nblk) hist[base + k] = run + sc - v;   // exclusive
        run += __shfl(sc, 63, 64);
    }
}

// ---------- P3: partition scatter, packed records src | dstLocal<<17 ----------
__global__ __launch_bounds__(256) void k_p3(
    const int* __restrict__ src, const int* __restrict__ dst, int E,
    const int* __restrict__ hist, int nblk, int nb, uint32* __restrict__ part) {
    __shared__ int cur[MAXB];
    for (int i = threadIdx.x; i < nb; i += 256) cur[i] = hist[(size_t)i * nblk + blockIdx.x];
    __syncthreads();
    int base = blockIdx.x * EPB;
    int lim = E - base; if (lim > EPB) lim = EPB;
    for (int j = threadIdx.x; j < lim; j += 256) {
        int d = dst[base + j];
        int s = src[base + j];
        int b = d >> BSHIFT;
        int pos = atomicAdd(&cur[b], 1);
        part[pos] = (uint32)s | ((uint32)(d & (BNODES - 1)) << 17);
    }
}

// ---------- per-bucket counting sort -> CSR (row_ptr, col) + dis ----------
__global__ __launch_bounds__(256) void k_sort(
    const uint32* __restrict__ part, const int* __restrict__ bstart,
    int* __restrict__ row_ptr, int* __restrict__ col, float* __restrict__ dis,
    int n, int nb) {
    __shared__ int cnt[BNODES];
    __shared__ int off[BNODES + 1];
    int b = blockIdx.x;
    int node0 = b << BSHIFT;
    int nn = n - node0; if (nn > BNODES) nn = BNODES;

    if (threadIdx.x < BNODES) cnt[threadIdx.x] = 0;
    __syncthreads();
    int beg = bstart[b], end = bstart[b + 1];
    for (int i = beg + threadIdx.x; i < end; i += 256)
        atomicAdd(&cnt[part[i] >> 17], 1);
    __syncthreads();
    if (threadIdx.x == 0) {
        int run = beg;
        for (int j = 0; j < BNODES; ++j) { off[j] = run; run += cnt[j]; }
        off[BNODES] = run;
    }
    __syncthreads();
    if (threadIdx.x < nn) {
        row_ptr[node0 + threadIdx.x] = off[threadIdx.x];
        dis[node0 + threadIdx.x] = rsqrtf((float)cnt[threadIdx.x] + 1.0f);  // +1 self-loop
    }
    if (b == nb - 1 && threadIdx.x == 0) row_ptr[n] = end;
    if (threadIdx.x < BNODES) cnt[threadIdx.x] = 0;   // reuse as cursor
    __syncthreads();
    for (int i = beg + threadIdx.x; i < end; i += 256) {
        uint32 p = part[i];
        int j = p >> 17;
        int pos = off[j] + atomicAdd(&cnt[j], 1);
        col[pos] = (int)(p & 0x1FFFFu);    // global src id (n < 2^17)
    }
}

// ---------- tall-skinny GEMM: g_bf16 = bf16((X @ W) * dis) ----------
// 4x4 register tile per thread; per k4-step: 8 x b128 LDS reads + 64 FMA
// (vs 68 scalar reads before). unroll 2 keeps VGPR ~70 (R11 spill lesson).
__global__ __launch_bounds__(256) void k_gemm_scale(
    const float* __restrict__ X, const float* __restrict__ W,
    const float* __restrict__ dis, ushort16* __restrict__ gb, int n) {
    __shared__ float Ws[64 * 64];       // [k][dout], stride 64
    __shared__ float Xs[64 * XPAD];     // [row][k],  stride 68

    {   // W float4 staging (layout matches global)
        float4* Wv = (float4*)Ws;
        const float4* Wg = (const float4*)W;
        for (int i = threadIdx.x; i < 64 * 16; i += 256) Wv[i] = Wg[i];
    }
    int row0 = blockIdx.x * 64;
    int rows = n - row0; if (rows > 64) rows = 64;
    {   // X float4 staging into padded rows
        const float4* Xg = (const float4*)(X + (size_t)row0 * 64);
        for (int i = threadIdx.x; i < rows * 16; i += 256) {
            int row = i >> 4, c = i & 15;
            ((float4*)(Xs + row * XPAD))[c] = Xg[i];
        }
    }
    __syncthreads();

    int tj = threadIdx.x & 15;    // col tile (cols 4tj..4tj+3)
    int ti = threadIdx.x >> 4;    // row tile (rows 4ti..4ti+3)

    float acc[4][4];
#pragma unroll
    for (int r = 0; r < 4; ++r)
#pragma unroll
        for (int c = 0; c < 4; ++c) acc[r][c] = 0.f;

#pragma unroll 2
    for (int k4 = 0; k4 < 64; k4 += 4) {
        float4 w0 = *(const float4*)(Ws + (k4 + 0) * 64 + 4 * tj);
        float4 w1 = *(const float4*)(Ws + (k4 + 1) * 64 + 4 * tj);
        float4 w2 = *(const float4*)(Ws + (k4 + 2) * 64 + 4 * tj);
        float4 w3 = *(const float4*)(Ws + (k4 + 3) * 64 + 4 * tj);
#pragma unroll
        for (int r = 0; r < 4; ++r) {
            float4 xv = *(const float4*)(Xs + (4 * ti + r) * XPAD + k4);
            acc[r][0] = fmaf(xv.x, w0.x, acc[r][0]);
            acc[r][1] = fmaf(xv.x, w0.y, acc[r][1]);
            acc[r][2] = fmaf(xv.x, w0.z, acc[r][2]);
            acc[r][3] = fmaf(xv.x, w0.w, acc[r][3]);
            acc[r][0] = fmaf(xv.y, w1.x, acc[r][0]);
            acc[r][1] = fmaf(xv.y, w1.y, acc[r][1]);
            acc[r][2] = fmaf(xv.y, w1.z, acc[r][2]);
            acc[r][3] = fmaf(xv.y, w1.w, acc[r][3]);
            acc[r][0] = fmaf(xv.z, w2.x, acc[r][0]);
            acc[r][1] = fmaf(xv.z, w2.y, acc[r][1]);
            acc[r][2] = fmaf(xv.z, w2.z, acc[r][2]);
            acc[r][3] = fmaf(xv.z, w2.w, acc[r][3]);
            acc[r][0] = fmaf(xv.w, w3.x, acc[r][0]);
            acc[r][1] = fmaf(xv.w, w3.y, acc[r][1]);
            acc[r][2] = fmaf(xv.w, w3.z, acc[r][2]);
            acc[r][3] = fmaf(xv.w, w3.w, acc[r][3]);
        }
    }

#pragma unroll
    for (int r = 0; r < 4; ++r) {
        int row = 4 * ti + r;
        if (row < rows) {
            float dn = dis[row0 + row];
            ushort4 o;
            o.x = f2bf(acc[r][0] * dn);
            o.y = f2bf(acc[r][1] * dn);
            o.z = f2bf(acc[r][2] * dn);
            o.w = f2bf(acc[r][3] * dn);
            *(ushort4*)(gb + (size_t)(row0 + row) * 64 + 4 * tj) = o;   // 8B coalesced
        }
    }
}

// ---------- fused aggregate + epilogue (wave per node, deep-MLP bf16 gather) ----------
// Lane = (slot 0..7) x (chunk 0..7). Each lane loads uint4 (8 bf16 feats) of row
// col[slot]; 16 neighbor edges (clamped/masked) per iteration -> 16 rows in
// flight per wave. Self row added once (slot 0) before the loop. 3-round
// shfl_xor folds the 8 slots at the end.
__global__ __launch_bounds__(256) void k_aggregate(
    const ushort16* __restrict__ gb, const int* __restrict__ row_ptr,
    const int* __restrict__ col, const float* __restrict__ dis,
    const float* __restrict__ bias, const float* __restrict__ resid,
    float* __restrict__ out, int n) {
    int node = blockIdx.x * 4 + (threadIdx.x >> 6);
    if (node >= n) return;
    int lane = threadIdx.x & 63;
    int slot = lane >> 3;     // edge slot 0..7
    int q    = lane & 7;      // 16B chunk 0..7 (feats q*8 .. q*8+7)
    const uint4* gq = (const uint4*)gb;   // row = 8 uint4

    int beg = row_ptr[node];
    int deg = row_ptr[node + 1] - beg;

    float acc[8];
#pragma unroll
    for (int j = 0; j < 8; ++j) acc[j] = 0.f;

    if (slot == 0) {   // self-loop term, once per q-chunk
        uint4 u = gq[(uint32)node * 8u + (uint32)q];
        acc[0] += bf_lo(u.x); acc[1] += bf_hi(u.x);
        acc[2] += bf_lo(u.y); acc[3] += bf_hi(u.y);
        acc[4] += bf_lo(u.z); acc[5] += bf_hi(u.z);
        acc[6] += bf_lo(u.w); acc[7] += bf_hi(u.w);
    }

    for (int i = 0; i < deg; i += 16) {
        int v0 = i + slot;
        int v1 = i + 8 + slot;
        int m = deg - 1;
        int c0 = col[beg + (v0 < m ? v0 : m)];
        int c1 = col[beg + (v1 < m ? v1 : m)];
        uint4 u0 = gq[(uint32)c0 * 8u + (uint32)q];
        uint4 u1 = gq[(uint32)c1 * 8u + (uint32)q];
        float w0 = (v0 < deg) ? 1.f : 0.f;
        float w1 = (v1 < deg) ? 1.f : 0.f;
        acc[0] = fmaf(w0, bf_lo(u0.x), acc[0]); acc[1] = fmaf(w0, bf_hi(u0.x), acc[1]);
        acc[2] = fmaf(w0, bf_lo(u0.y), acc[2]); acc[3] = fmaf(w0, bf_hi(u0.y), acc[3]);
        acc[4] = fmaf(w0, bf_lo(u0.z), acc[4]); acc[5] = fmaf(w0, bf_hi(u0.z), acc[5]);
        acc[6] = fmaf(w0, bf_lo(u0.w), acc[6]); acc[7] = fmaf(w0, bf_hi(u0.w), acc[7]);
        acc[0] = fmaf(w1, bf_lo(u1.x), acc[0]); acc[1] = fmaf(w1, bf_hi(u1.x), acc[1]);
        acc[2] = fmaf(w1, bf_lo(u1.y), acc[2]); acc[3] = fmaf(w1, bf_hi(u1.y), acc[3]);
        acc[4] = fmaf(w1, bf_lo(u1.z), acc[4]); acc[5] = fmaf(w1, bf_hi(u1.z), acc[5]);
        acc[6] = fmaf(w1, bf_lo(u1.w), acc[6]); acc[7] = fmaf(w1, bf_hi(u1.w), acc[7]);
    }

    // fold the 8 slots (lanes q, q+8, ..., q+56)
#pragma unroll
    for (int j = 0; j < 8; ++j) {
        acc[j] += __shfl_xor(acc[j], 8, 64);
        acc[j] += __shfl_xor(acc[j], 16, 64);
        acc[j] += __shfl_xor(acc[j], 32, 64);
    }

    if (slot == 0) {          // lanes 0..7, lane == q
        float dn = dis[node];
        float r[8];
#pragma unroll
        for (int j = 0; j < 8; ++j)
            r[j] = fmaxf(fmaf(acc[j], dn, bias[q * 8 + j]), 0.f);
        if (resid) {
            const float4* rv = (const float4*)(resid + (size_t)node * DFEAT + q * 8);
            float4 x0 = rv[0], x1 = rv[1];
            r[0] += x0.x; r[1] += x0.y; r[2] += x0.z; r[3] += x0.w;
            r[4] += x1.x; r[5] += x1.y; r[6] += x1.z; r[7] += x1.w;
        }
        float4* ov = (float4*)(out + (size_t)node * DFEAT + q * 8);
        ov[0] = make_float4(r[0], r[1], r[2], r[3]);
        ov[1] = make_float4(r[4], r[5], r[6], r[7]);
    }
}

// ======================= launch =======================

extern "C" void kernel_launch(void* const* d_in, const int* in_sizes, int n_in,
                              void* d_out, int out_size, void* d_ws, size_t ws_size,
                              hipStream_t stream) {
    const float* x  = (const float*)d_in[0];
    const int*   ei = (const int*)  d_in[1];
    const float* W1 = (const float*)d_in[2];
    const float* b1 = (const float*)d_in[3];
    const float* W2 = (const float*)d_in[4];
    const float* b2 = (const float*)d_in[5];
    float* out = (float*)d_out;

    const int n = in_sizes[0] / DFEAT;     // 100000
    const int E = in_sizes[1] / 2;         // 1250000
    const int* src = ei;
    const int* dst = ei + E;

    const int nb   = (n + BNODES - 1) >> BSHIFT;     // 782 buckets
    const int nblk = (E + EPB - 1) / EPB;            // 306 partition blocks

    // workspace carve-up (4B elems)
    int*      hist    = (int*)d_ws;                                  // nb*nblk
    int*      btot    = hist + (((size_t)nb * nblk + 3) & ~3);       // nb
    int*      bstart  = btot + ((nb + 3) & ~3);                      // nb+1
    uint32*   part    = (uint32*)(bstart + ((nb + 1 + 3) & ~3));     // E
    int*      row_ptr = (int*)(part + ((E + 3) & ~3));               // n+1
    int*      col     = row_ptr + ((n + 1 + 3) & ~3);                // E
    float*    dis     = (float*)(col + ((E + 3) & ~3));              // n
    ushort16* gb      = (ushort16*)(dis + ((n + 3) & ~3));           // n*64 bf16
    float*    h       = (float*)(gb + (size_t)n * DFEAT);            // n*64 f32

    const int B256 = 256;
    const int gT   = (n + 63) / 64;
    const int gW   = ((nb * 64) + B256 - 1) / B256;   // wave-per-bucket kernels
    const int gAg  = (n + 3) / 4;

    // ---- bucket partition + per-bucket sort -> CSR ----
    k_p1  <<<nblk, B256, 0, stream>>>(dst, E, hist, nblk, nb);
    k_p2a <<<gW,   B256, 0, stream>>>(hist, nblk, nb, btot);
    k_p2b <<<1,    B256, 0, stream>>>(btot, nb, bstart);
    k_p2c <<<gW,   B256, 0, stream>>>(hist, nblk, nb, bstart);
    k_p3  <<<nblk, B256, 0, stream>>>(src, dst, E, hist, nblk, nb, part);
    k_sort<<<nb,   B256, 0, stream>>>(part, bstart, row_ptr, col, dis, n, nb);

    // ---- layer 1 ----
    k_gemm_scale<<<gT,  B256, 0, stream>>>(x, W1, dis, gb, n);
    k_aggregate <<<gAg, B256, 0, stream>>>(gb, row_ptr, col, dis, b1, nullptr, h, n);

    // ---- layer 2 ----
    k_gemm_scale<<<gT,  B256, 0, stream>>>(h, W2, dis, gb, n);
    k_aggregate <<<gAg, B256, 0, stream>>>(gb, row_ptr, col, dis, b2, x, out, n);
}

// Round 17
// 236.059 us; speedup vs baseline: 5.6551x; 1.0154x over previous
//
#include <hip/hip_runtime.h>

#define DFEAT 64
#define BSHIFT 7                 // 128 nodes per bucket
#define BNODES 128
#define MAXB 1024                // supports n <= 131072 nodes, nb <= 1024 buckets
#define EPB 4096                 // edges per partition block
#define XPAD 68                  // Xs row stride (pad 4 floats: 2-way bank alias, free)

typedef unsigned int uint32;
typedef unsigned short ushort16;

// ---------- bf16 helpers ----------
__device__ __forceinline__ ushort16 f2bf(float f) {
    uint32 u = __float_as_uint(f);
    u += 0x7fffu + ((u >> 16) & 1u);   // round-to-nearest-even
    return (ushort16)(u >> 16);
}
__device__ __forceinline__ float bf_lo(uint32 u) { return __uint_as_float(u << 16); }
__device__ __forceinline__ float bf_hi(uint32 u) { return __uint_as_float(u & 0xffff0000u); }

// ---------- P1: per-block bucket histogram (1024 thr: 4.8 waves/SIMD) ----------
__global__ __launch_bounds__(1024) void k_p1(
    const int* __restrict__ dst, int E, int* __restrict__ hist, int nblk, int nb) {
    __shared__ int h[MAXB];
    for (int i = threadIdx.x; i < nb; i += 1024) h[i] = 0;
    __syncthreads();
    int base = blockIdx.x * EPB;
    int lim = E - base; if (lim > EPB) lim = EPB;
    for (int j = threadIdx.x; j < lim; j += 1024)
        atomicAdd(&h[dst[base + j] >> BSHIFT], 1);
    __syncthreads();
    for (int i = threadIdx.x; i < nb; i += 1024)
        hist[(size_t)i * nblk + blockIdx.x] = h[i];   // bucket-major rows
}

// ---------- P2a: bucket totals (one wave per bucket) ----------
__global__ __launch_bounds__(256) void k_p2a(
    const int* __restrict__ hist, int nblk, int nb, int* __restrict__ btot) {
    int w = (blockIdx.x * 256 + threadIdx.x) >> 6;
    int lane = threadIdx.x & 63;
    if (w >= nb) return;
    size_t base = (size_t)w * nblk;
    int s = 0;
    for (int k = lane; k < nblk; k += 64) s += hist[base + k];
#pragma unroll
    for (int d = 1; d < 64; d <<= 1) s += __shfl_xor(s, d, 64);
    if (lane == 0) btot[w] = s;
}

// ---------- P2b: exclusive scan of bucket totals (nb <= 1024), wave-parallel ----------
__global__ __launch_bounds__(256) void k_p2b(
    const int* __restrict__ btot, int nb, int* __restrict__ bstart) {
    __shared__ int wsum[4];
    int t = threadIdx.x;
    int lane = t & 63, w = t >> 6;
    int c0 = t * 4;
    int v[4]; int s = 0;
#pragma unroll
    for (int j = 0; j < 4; ++j) { v[j] = (c0 + j < nb) ? btot[c0 + j] : 0; s += v[j]; }
    int sc = s;                          // wave-inclusive scan
#pragma unroll
    for (int d = 1; d < 64; d <<= 1) { int tt = __shfl_up(sc, d, 64); if (lane >= d) sc += tt; }
    if (lane == 63) wsum[w] = sc;
    __syncthreads();
    int base = 0;
    for (int k = 0; k < w; ++k) base += wsum[k];
    int run = base + sc - s;             // exclusive prefix for this thread's 4
#pragma unroll
    for (int j = 0; j < 4; ++j) {
        if (c0 + j < nb) bstart[c0 + j] = run;
        run += v[j];
    }
    if (t == 255) bstart[nb] = base + sc;   // = E
}

// ---------- P2c: per-(bucket,block) global offsets, wave-parallel scan per bucket ----------
__global__ __launch_bounds__(256) void k_p2c(
    int* __restrict__ hist, int nblk, int nb, const int* __restrict__ bstart) {
    int w = (blockIdx.x * 256 + threadIdx.x) >> 6;
    int lane = threadIdx.x & 63;
    if (w >= nb) return;
    size_t base = (size_t)w * nblk;
    int run = bstart[w];
    for (int c = 0; c < nblk; c += 64) {
        int k = c + lane;
        int v = (k < nblk) ? hist[base + k] : 0;
        int sc = v;
#pragma unroll
        for (int d = 1; d < 64; d <<= 1) { int t = __shfl_up(sc, d, 64); if (lane >= d) sc += t; }
        if (k < nblk) hist[base + k] = run + sc - v;   // exclusive
        run += __shfl(sc, 63, 64);
    }
}

// ---------- P3: partition scatter, packed records src | dstLocal<<17 ----------
__global__ __launch_bounds__(1024) void k_p3(
    const int* __restrict__ src, const int* __restrict__ dst, int E,
    const int* __restrict__ hist, int nblk, int nb, uint32* __restrict__ part) {
    __shared__ int cur[MAXB];
    for (int i = threadIdx.x; i < nb; i += 1024) cur[i] = hist[(size_t)i * nblk + blockIdx.x];
    __syncthreads();
    int base = blockIdx.x * EPB;
    int lim = E - base; if (lim > EPB) lim = EPB;
    for (int j = threadIdx.x; j < lim; j += 1024) {
        int d = dst[base + j];
        int s = src[base + j];
        int b = d >> BSHIFT;
        int pos = atomicAdd(&cur[b], 1);
        part[pos] = (uint32)s | ((uint32)(d & (BNODES - 1)) << 17);
    }
}

// ---------- per-bucket counting sort -> CSR (row_ptr, col) + dis ----------
// off[] scan now wave-parallel (was a 128-iter serial LDS loop on thread 0).
__global__ __launch_bounds__(256) void k_sort(
    const uint32* __restrict__ part, const int* __restrict__ bstart,
    int* __restrict__ row_ptr, int* __restrict__ col, float* __restrict__ dis,
    int n, int nb) {
    __shared__ int cnt[BNODES];
    __shared__ int off[BNODES + 1];
    int b = blockIdx.x;
    int node0 = b << BSHIFT;
    int nn = n - node0; if (nn > BNODES) nn = BNODES;

    if (threadIdx.x < BNODES) cnt[threadIdx.x] = 0;
    __syncthreads();
    int beg = bstart[b], end = bstart[b + 1];
    for (int i = beg + threadIdx.x; i < end; i += 256)
        atomicAdd(&cnt[part[i] >> 17], 1);
    __syncthreads();
    if (threadIdx.x < 64) {              // wave 0: parallel scan, 2 elems/lane
        int l = threadIdx.x;
        int c0 = cnt[2 * l], c1 = cnt[2 * l + 1];
        int s = c0 + c1;
        int sc = s;
#pragma unroll
        for (int d = 1; d < 64; d <<= 1) { int tt = __shfl_up(sc, d, 64); if (l >= d) sc += tt; }
        int ex = beg + sc - s;
        off[2 * l] = ex;
        off[2 * l + 1] = ex + c0;
        if (l == 63) off[BNODES] = ex + s;   // = end
    }
    __syncthreads();
    if (threadIdx.x < nn) {
        row_ptr[node0 + threadIdx.x] = off[threadIdx.x];
        dis[node0 + threadIdx.x] = rsqrtf((float)cnt[threadIdx.x] + 1.0f);  // +1 self-loop
    }
    if (b == nb - 1 && threadIdx.x == 0) row_ptr[n] = end;
    if (threadIdx.x < BNODES) cnt[threadIdx.x] = 0;   // reuse as cursor
    __syncthreads();
    for (int i = beg + threadIdx.x; i < end; i += 256) {
        uint32 p = part[i];
        int j = p >> 17;
        int pos = off[j] + atomicAdd(&cnt[j], 1);
        col[pos] = (int)(p & 0x1FFFFu);    // global src id (n < 2^17)
    }
}

// ---------- tall-skinny GEMM: g_bf16 = bf16((X @ W) * dis) ----------
// 4x4 register tile per thread; per k4-step: 8 x b128 LDS reads + 64 FMA.
// unroll 2 keeps VGPR ~70 (R11 spill lesson).
__global__ __launch_bounds__(256) void k_gemm_scale(
    const float* __restrict__ X, const float* __restrict__ W,
    const float* __restrict__ dis, ushort16* __restrict__ gb, int n) {
    __shared__ float Ws[64 * 64];       // [k][dout], stride 64
    __shared__ float Xs[64 * XPAD];     // [row][k],  stride 68

    {   // W float4 staging (layout matches global)
        float4* Wv = (float4*)Ws;
        const float4* Wg = (const float4*)W;
        for (int i = threadIdx.x; i < 64 * 16; i += 256) Wv[i] = Wg[i];
    }
    int row0 = blockIdx.x * 64;
    int rows = n - row0; if (rows > 64) rows = 64;
    {   // X float4 staging into padded rows
        const float4* Xg = (const float4*)(X + (size_t)row0 * 64);
        for (int i = threadIdx.x; i < rows * 16; i += 256) {
            int row = i >> 4, c = i & 15;
            ((float4*)(Xs + row * XPAD))[c] = Xg[i];
        }
    }
    __syncthreads();

    int tj = threadIdx.x & 15;    // col tile (cols 4tj..4tj+3)
    int ti = threadIdx.x >> 4;    // row tile (rows 4ti..4ti+3)

    float acc[4][4];
#pragma unroll
    for (int r = 0; r < 4; ++r)
#pragma unroll
        for (int c = 0; c < 4; ++c) acc[r][c] = 0.f;

#pragma unroll 2
    for (int k4 = 0; k4 < 64; k4 += 4) {
        float4 w0 = *(const float4*)(Ws + (k4 + 0) * 64 + 4 * tj);
        float4 w1 = *(const float4*)(Ws + (k4 + 1) * 64 + 4 * tj);
        float4 w2 = *(const float4*)(Ws + (k4 + 2) * 64 + 4 * tj);
        float4 w3 = *(const float4*)(Ws + (k4 + 3) * 64 + 4 * tj);
#pragma unroll
        for (int r = 0; r < 4; ++r) {
            float4 xv = *(const float4*)(Xs + (4 * ti + r) * XPAD + k4);
            acc[r][0] = fmaf(xv.x, w0.x, acc[r][0]);
            acc[r][1] = fmaf(xv.x, w0.y, acc[r][1]);
            acc[r][2] = fmaf(xv.x, w0.z, acc[r][2]);
            acc[r][3] = fmaf(xv.x, w0.w, acc[r][3]);
            acc[r][0] = fmaf(xv.y, w1.x, acc[r][0]);
            acc[r][1] = fmaf(xv.y, w1.y, acc[r][1]);
            acc[r][2] = fmaf(xv.y, w1.z, acc[r][2]);
            acc[r][3] = fmaf(xv.y, w1.w, acc[r][3]);
            acc[r][0] = fmaf(xv.z, w2.x, acc[r][0]);
            acc[r][1] = fmaf(xv.z, w2.y, acc[r][1]);
            acc[r][2] = fmaf(xv.z, w2.z, acc[r][2]);
            acc[r][3] = fmaf(xv.z, w2.w, acc[r][3]);
            acc[r][0] = fmaf(xv.w, w3.x, acc[r][0]);
            acc[r][1] = fmaf(xv.w, w3.y, acc[r][1]);
            acc[r][2] = fmaf(xv.w, w3.z, acc[r][2]);
            acc[r][3] = fmaf(xv.w, w3.w, acc[r][3]);
        }
    }

#pragma unroll
    for (int r = 0; r < 4; ++r) {
        int row = 4 * ti + r;
        if (row < rows) {
            float dn = dis[row0 + row];
            ushort4 o;
            o.x = f2bf(acc[r][0] * dn);
            o.y = f2bf(acc[r][1] * dn);
            o.z = f2bf(acc[r][2] * dn);
            o.w = f2bf(acc[r][3] * dn);
            *(ushort4*)(gb + (size_t)(row0 + row) * 64 + 4 * tj) = o;   // 8B coalesced
        }
    }
}

// ---------- fused aggregate + epilogue (wave per node, deep-MLP bf16 gather) ----------
// Lane = (slot 0..7) x (chunk 0..7); uint4 row gathers, 16 edges/iter in flight.
// Wave-uniform deg<=8 fast path (single gather). 3-round shfl_xor slot fold.
__global__ __launch_bounds__(256) void k_aggregate(
    const ushort16* __restrict__ gb, const int* __restrict__ row_ptr,
    const int* __restrict__ col, const float* __restrict__ dis,
    const float* __restrict__ bias, const float* __restrict__ resid,
    float* __restrict__ out, int n) {
    int node = blockIdx.x * 4 + (threadIdx.x >> 6);
    if (node >= n) return;
    int lane = threadIdx.x & 63;
    int slot = lane >> 3;     // edge slot 0..7
    int q    = lane & 7;      // 16B chunk 0..7 (feats q*8 .. q*8+7)
    const uint4* gq = (const uint4*)gb;   // row = 8 uint4

    int beg = row_ptr[node];
    int deg = row_ptr[node + 1] - beg;

    float acc[8];
#pragma unroll
    for (int j = 0; j < 8; ++j) acc[j] = 0.f;

    if (slot == 0) {   // self-loop term, once per q-chunk
        uint4 u = gq[(uint32)node * 8u + (uint32)q];
        acc[0] += bf_lo(u.x); acc[1] += bf_hi(u.x);
        acc[2] += bf_lo(u.y); acc[3] += bf_hi(u.y);
        acc[4] += bf_lo(u.z); acc[5] += bf_hi(u.z);
        acc[6] += bf_lo(u.w); acc[7] += bf_hi(u.w);
    }

    if (deg > 0 && deg <= 8) {          // wave-uniform fast path: one gather
        int m = deg - 1;
        int c0 = col[beg + (slot < m ? slot : m)];
        uint4 u0 = gq[(uint32)c0 * 8u + (uint32)q];
        float w0 = (slot < deg) ? 1.f : 0.f;
        acc[0] = fmaf(w0, bf_lo(u0.x), acc[0]); acc[1] = fmaf(w0, bf_hi(u0.x), acc[1]);
        acc[2] = fmaf(w0, bf_lo(u0.y), acc[2]); acc[3] = fmaf(w0, bf_hi(u0.y), acc[3]);
        acc[4] = fmaf(w0, bf_lo(u0.z), acc[4]); acc[5] = fmaf(w0, bf_hi(u0.z), acc[5]);
        acc[6] = fmaf(w0, bf_lo(u0.w), acc[6]); acc[7] = fmaf(w0, bf_hi(u0.w), acc[7]);
    } else {
        for (int i = 0; i < deg; i += 16) {
            int v0 = i + slot;
            int v1 = i + 8 + slot;
            int m = deg - 1;
            int c0 = col[beg + (v0 < m ? v0 : m)];
            int c1 = col[beg + (v1 < m ? v1 : m)];
            uint4 u0 = gq[(uint32)c0 * 8u + (uint32)q];
            uint4 u1 = gq[(uint32)c1 * 8u + (uint32)q];
            float w0 = (v0 < deg) ? 1.f : 0.f;
            float w1 = (v1 < deg) ? 1.f : 0.f;
            acc[0] = fmaf(w0, bf_lo(u0.x), acc[0]); acc[1] = fmaf(w0, bf_hi(u0.x), acc[1]);
            acc[2] = fmaf(w0, bf_lo(u0.y), acc[2]); acc[3] = fmaf(w0, bf_hi(u0.y), acc[3]);
            acc[4] = fmaf(w0, bf_lo(u0.z), acc[4]); acc[5] = fmaf(w0, bf_hi(u0.z), acc[5]);
            acc[6] = fmaf(w0, bf_lo(u0.w), acc[6]); acc[7] = fmaf(w0, bf_hi(u0.w), acc[7]);
            acc[0] = fmaf(w1, bf_lo(u1.x), acc[0]); acc[1] = fmaf(w1, bf_hi(u1.x), acc[1]);
            acc[2] = fmaf(w1, bf_lo(u1.y), acc[2]); acc[3] = fmaf(w1, bf_hi(u1.y), acc[3]);
            acc[4] = fmaf(w1, bf_lo(u1.z), acc[4]); acc[5] = fmaf(w1, bf_hi(u1.z), acc[5]);
            acc[6] = fmaf(w1, bf_lo(u1.w), acc[6]); acc[7] = fmaf(w1, bf_hi(u1.w), acc[7]);
        }
    }

    // fold the 8 slots (lanes q, q+8, ..., q+56)
#pragma unroll
    for (int j = 0; j < 8; ++j) {
        acc[j] += __shfl_xor(acc[j], 8, 64);
        acc[j] += __shfl_xor(acc[j], 16, 64);
        acc[j] += __shfl_xor(acc[j], 32, 64);
    }

    if (slot == 0) {          // lanes 0..7, lane == q
        float dn = dis[node];
        float r[8];
#pragma unroll
        for (int j = 0; j < 8; ++j)
            r[j] = fmaxf(fmaf(acc[j], dn, bias[q * 8 + j]), 0.f);
        if (resid) {
            const float4* rv = (const float4*)(resid + (size_t)node * DFEAT + q * 8);
            float4 x0 = rv[0], x1 = rv[1];
            r[0] += x0.x; r[1] += x0.y; r[2] += x0.z; r[3] += x0.w;
            r[4] += x1.x; r[5] += x1.y; r[6] += x1.z; r[7] += x1.w;
        }
        float4* ov = (float4*)(out + (size_t)node * DFEAT + q * 8);
        ov[0] = make_float4(r[0], r[1], r[2], r[3]);
        ov[1] = make_float4(r[4], r[5], r[6], r[7]);
    }
}

// ======================= launch =======================

extern "C" void kernel_launch(void* const* d_in, const int* in_sizes, int n_in,
                              void* d_out, int out_size, void* d_ws, size_t ws_size,
                              hipStream_t stream) {
    const float* x  = (const float*)d_in[0];
    const int*   ei = (const int*)  d_in[1];
    const float* W1 = (const float*)d_in[2];
    const float* b1 = (const float*)d_in[3];
    const float* W2 = (const float*)d_in[4];
    const float* b2 = (const float*)d_in[5];
    float* out = (float*)d_out;

    const int n = in_sizes[0] / DFEAT;     // 100000
    const int E = in_sizes[1] / 2;         // 1250000
    const int* src = ei;
    const int* dst = ei + E;

    const int nb   = (n + BNODES - 1) >> BSHIFT;     // 782 buckets
    const int nblk = (E + EPB - 1) / EPB;            // 306 partition blocks

    // workspace carve-up (4B elems)
    int*      hist    = (int*)d_ws;                                  // nb*nblk
    int*      btot    = hist + (((size_t)nb * nblk + 3) & ~3);       // nb
    int*      bstart  = btot + ((nb + 3) & ~3);                      // nb+1
    uint32*   part    = (uint32*)(bstart + ((nb + 1 + 3) & ~3));     // E
    int*      row_ptr = (int*)(part + ((E + 3) & ~3));               // n+1
    int*      col     = row_ptr + ((n + 1 + 3) & ~3);                // E
    float*    dis     = (float*)(col + ((E + 3) & ~3));              // n
    ushort16* gb      = (ushort16*)(dis + ((n + 3) & ~3));           // n*64 bf16
    float*    h       = (float*)(gb + (size_t)n * DFEAT);            // n*64 f32

    const int B256 = 256;
    const int gT   = (n + 63) / 64;
    const int gW   = ((nb * 64) + B256 - 1) / B256;   // wave-per-bucket kernels
    const int gAg  = (n + 3) / 4;

    // ---- bucket partition + per-bucket sort -> CSR ----
    k_p1  <<<nblk, 1024, 0, stream>>>(dst, E, hist, nblk, nb);
    k_p2a <<<gW,   B256, 0, stream>>>(hist, nblk, nb, btot);
    k_p2b <<<1,    B256, 0, stream>>>(btot, nb, bstart);
    k_p2c <<<gW,   B256, 0, stream>>>(hist, nblk, nb, bstart);
    k_p3  <<<nblk, 1024, 0, stream>>>(src, dst, E, hist, nblk, nb, part);
    k_sort<<<nb,   B256, 0, stream>>>(part, bstart, row_ptr, col, dis, n, nb);

    // ---- layer 1 ----
    k_gemm_scale<<<gT,  B256, 0, stream>>>(x, W1, dis, gb, n);
    k_aggregate <<<gAg, B256, 0, stream>>>(gb, row_ptr, col, dis, b1, nullptr, h, n);

    // ---- layer 2 ----
    k_gemm_scale<<<gT,  B256, 0, stream>>>(h, W2, dis, gb, n);
    k_aggregate <<<gAg, B256, 0, stream>>>(gb, row_ptr, col, dis, b2, x, out, n);
}